// Round 13
// baseline (569.864 us; speedup 1.0000x reference)
//
#include <hip/hip_runtime.h>
#include <hip/hip_fp8.h>
#include <math.h>

// ---------------------------------------------------------------------------
// GATClassifier on MI355X.
//   1. CSR build over dst (histogram -> 3-phase scan -> scatter w/ colsrc+coldst)
//   2. Per layer: split-bf16 MFMA GEMM (LDS-staged A, read-once, R13:
//      double-buffered + 1-step prefetch + 1 barrier/k-step, 32 rows/block —
//      R12 showed 2-barrier version latency-bound: Mfma 12.5%, VALU 15%,
//      HBM 15%, Occ 19.5%); h stored bf16-hi + fp8 copy; att dots from bf16;
//      dense edge-parallel exp(leaky()) -> bf16 ealpha; agg = gather-only
//      serial loop accumulating acc += w*row and den += w per lane.
//   3. Fused mean-pool + 32->1 linear (batch sorted -> binary search)
// History: R2 pool 383. R3 SGEMM 158x2. R4 agg 155x2. R5 gemm 140x2. R6 agg
// 131x2. R7 scan 111. R8 agg 87x2. R9 gemm 89x2. R10 agg 80x2. R11 agg 71x2.
// R12 gemm_lds 57x2 (barrier-drain latency) -> R13 dbuf+prefetch.
// NOTE: edge_index / batch are int32.
// ---------------------------------------------------------------------------

typedef __attribute__((ext_vector_type(8))) __bf16 bf16x8;
typedef __attribute__((ext_vector_type(4))) __bf16 bf16x4;
typedef __attribute__((ext_vector_type(4))) float f32x4;
typedef __attribute__((ext_vector_type(2))) float f32x2;

#define SCAN_CH 4  // elements per thread in the device-wide scan

__device__ inline unsigned char f32_to_fp8(float f) {
  __hip_fp8_e4m3 v(f);
  return (unsigned char)v.__x;
}
__device__ inline float fp8_to_f32(unsigned char u) {
  __hip_fp8_e4m3 v;
  v.__x = (__hip_fp8_storage_t)u;
  return (float)v;
}

// Decode 4 packed fp8-e4m3 bytes -> 4 floats, accumulate w * val into acc.
__device__ inline void fma_fp8x4(f32x4& acc, float w, unsigned int packed) {
#if defined(__has_builtin) && __has_builtin(__builtin_amdgcn_cvt_pk_f32_fp8)
  f32x2 lo = __builtin_amdgcn_cvt_pk_f32_fp8((int)packed, false);  // bytes 0,1
  f32x2 hi = __builtin_amdgcn_cvt_pk_f32_fp8((int)packed, true);   // bytes 2,3
  acc[0] += w * lo[0];
  acc[1] += w * lo[1];
  acc[2] += w * hi[0];
  acc[3] += w * hi[1];
#else
  acc[0] += w * fp8_to_f32((unsigned char)(packed & 0xff));
  acc[1] += w * fp8_to_f32((unsigned char)((packed >> 8) & 0xff));
  acc[2] += w * fp8_to_f32((unsigned char)((packed >> 16) & 0xff));
  acc[3] += w * fp8_to_f32((unsigned char)(packed >> 24));
#endif
}

// ---------------- CSR build ----------------
__global__ __launch_bounds__(256) void k_init_deg(int* deg, int N) {
  int n = blockIdx.x * 256 + threadIdx.x;
  if (n < N) deg[n] = 1;  // self-loop
}

__global__ __launch_bounds__(256) void k_count_deg(const int* __restrict__ ei,
                                                   int E, int* deg) {
  int e = blockIdx.x * 256 + threadIdx.x;
  if (e < E) atomicAdd(&deg[ei[E + e]], 1);
}

// --- 3-phase exclusive scan (R8: old single-block scan was 111us on 1 CU) ---
__global__ __launch_bounds__(256) void k_scan_partial(const int* __restrict__ deg,
                                                      int* __restrict__ blockSums,
                                                      int N) {
  __shared__ int sh[256];
  int t = threadIdx.x, b = blockIdx.x;
  int base = (b * 256 + t) * SCAN_CH;
  int s = 0;
#pragma unroll
  for (int j = 0; j < SCAN_CH; j++) {
    int idx = base + j;
    if (idx < N) s += deg[idx];
  }
  sh[t] = s;
  __syncthreads();
  for (int off = 128; off > 0; off >>= 1) {
    if (t < off) sh[t] += sh[t + off];
    __syncthreads();
  }
  if (t == 0) blockSums[b] = sh[0];
}

__global__ __launch_bounds__(256) void k_scan_blocksums(
    const int* __restrict__ blockSums, int* __restrict__ blockOffs,
    int* __restrict__ rowptr, int nb, int N) {
  __shared__ int sh[256];
  int t = threadIdx.x;
  int v = (t < nb) ? blockSums[t] : 0;
  sh[t] = v;
  __syncthreads();
  for (int off = 1; off < 256; off <<= 1) {
    int u = (t >= off) ? sh[t - off] : 0;
    __syncthreads();
    sh[t] += u;
    __syncthreads();
  }
  if (t < nb) blockOffs[t] = sh[t] - v;  // exclusive
  if (t == nb - 1) rowptr[N] = sh[t];    // total
}

__global__ __launch_bounds__(256) void k_scan_final(const int* __restrict__ deg,
                                                    const int* __restrict__ blockOffs,
                                                    int* __restrict__ rowptr,
                                                    int* __restrict__ cursor, int N) {
  __shared__ int sh[256];
  int t = threadIdx.x, b = blockIdx.x;
  int base = (b * 256 + t) * SCAN_CH;
  int vals[SCAN_CH];
  int s = 0;
#pragma unroll
  for (int j = 0; j < SCAN_CH; j++) {
    int idx = base + j;
    vals[j] = (idx < N) ? deg[idx] : 0;
    s += vals[j];
  }
  sh[t] = s;
  __syncthreads();
  for (int off = 1; off < 256; off <<= 1) {
    int u = (t >= off) ? sh[t - off] : 0;
    __syncthreads();
    sh[t] += u;
    __syncthreads();
  }
  int run = blockOffs[b] + sh[t] - s;  // exclusive prefix for this thread
#pragma unroll
  for (int j = 0; j < SCAN_CH; j++) {
    int idx = base + j;
    if (idx < N) {
      rowptr[idx] = run;
      cursor[idx] = run;
      run += vals[j];
    }
  }
}

__global__ __launch_bounds__(256) void k_scatter(const int* __restrict__ ei,
                                                 int E, int N, int* cursor,
                                                 int* __restrict__ colsrc,
                                                 int* __restrict__ coldst) {
  int i = blockIdx.x * 256 + threadIdx.x;
  if (i < E) {
    int s = ei[i];
    int d = ei[E + i];
    int pos = atomicAdd(&cursor[d], 1);
    colsrc[pos] = s;
    coldst[pos] = d;
  } else if (i < E + N) {
    int nn = i - E;
    int pos = atomicAdd(&cursor[nn], 1);
    colsrc[pos] = nn;  // self loop
    coldst[pos] = nn;
  }
}

// ---------------- split-cast preps ----------------
__global__ __launch_bounds__(256) void k_split(const float* __restrict__ in,
                                               __bf16* __restrict__ oh,
                                               __bf16* __restrict__ ol, int n4) {
  int i = blockIdx.x * 256 + threadIdx.x;
  if (i >= n4) return;
  float4 v = ((const float4*)in)[i];
  bf16x4 h, l;
  h[0] = (__bf16)v.x; l[0] = (__bf16)(v.x - (float)h[0]);
  h[1] = (__bf16)v.y; l[1] = (__bf16)(v.y - (float)h[1]);
  h[2] = (__bf16)v.z; l[2] = (__bf16)(v.z - (float)h[2]);
  h[3] = (__bf16)v.w; l[3] = (__bf16)(v.w - (float)h[3]);
  ((bf16x4*)oh)[i] = h;
  ((bf16x4*)ol)[i] = l;
}

// W [K][Nc] fp32 -> WT hi/lo [Nc][K] bf16 (transposed so B-frags load b128).
__global__ __launch_bounds__(256) void k_wprep(const float* __restrict__ W,
                                               __bf16* __restrict__ WTh,
                                               __bf16* __restrict__ WTl,
                                               int K, int Nc) {
  int i = blockIdx.x * 256 + threadIdx.x;  // i = n*K + k
  if (i >= K * Nc) return;
  int n = i / K, k = i - n * K;
  float w = W[k * Nc + n];
  __bf16 h = (__bf16)w;
  WTh[i] = h;
  WTl[i] = (__bf16)(w - (float)h);
}

// ---------------- LDS-shared split-bf16 MFMA GEMM (layers 1/2, R13) ------
// Block = 32 rows x 256 cols (1564 blocks -> ~6/CU). Per 32-k step the A
// tile (32x32 hi+lo, 4KB) lives in a DOUBLE-BUFFERED LDS stage: A(k+1) is
// global-loaded at the top of step k and written to the alternate buffer
// AFTER the MFMAs (load has the whole compute phase to land), with ONE
// barrier per step (R12: 2-barrier version drained the 900-cyc HBM load
// every step -> Mfma 12.5%, Occ 19.5%). Staging: threads 0-127 hi,
// 128-255 lo, fragment-order. Wave = 2 m-tiles x 4 col-tiles.
// mfma_f32_16x16x32_bf16 (m89-verified): A: m=lane&15,k=quad*8+j;
// B: n=lane&15,k=quad*8+j (from WT); C/D: row=quad*4+reg, col=lane&15.
__global__ __launch_bounds__(256) void k_gemm_lds(
    const __bf16* __restrict__ Ah, const __bf16* __restrict__ Al,
    const __bf16* __restrict__ BTh, const __bf16* __restrict__ BTl,
    __bf16* __restrict__ Ch, unsigned char* __restrict__ Cf8, int M, int K) {
  constexpr int NcFull = 256;
  __shared__ __bf16 sAh[2][1024];  // [buf][(mt*4+kq)*16+l16][8]
  __shared__ __bf16 sAl[2][1024];
  int tid = threadIdx.x;
  int lane = tid & 63, wave = tid >> 6;
  int quad = lane >> 4, l16 = lane & 15;
  int m0 = blockIdx.x * 32;
  int col0 = wave * 64;
  // staging map: tt = tid&127 -> row sr = tt>>2 (0..31), k-quad skq = tt&3;
  // tid<128 stages hi, tid>=128 stages lo. One b128 load+store per step.
  int tt = tid & 127;
  int sr = tt >> 2, skq = tt & 3;
  int slot8 = (((sr >> 4) * 4 + skq) * 16 + (sr & 15)) * 8;
  int arow = min(m0 + sr, M - 1);  // clamp: rows >= M never stored
  const __bf16* ag = (tid < 128 ? Ah : Al) + (size_t)arow * K + skq * 8;
  __bf16* st0 = (tid < 128 ? sAh[0] : sAl[0]) + slot8;
  __bf16* st1 = (tid < 128 ? sAh[1] : sAl[1]) + slot8;
  const __bf16* brh = BTh + (size_t)(col0 + l16) * K + quad * 8;
  const __bf16* brl = BTl + (size_t)(col0 + l16) * K + quad * 8;
  f32x4 acc[2][4];  // [mt][nt]
#pragma unroll
  for (int mt = 0; mt < 2; mt++)
#pragma unroll
    for (int t = 0; t < 4; t++) acc[mt][t] = (f32x4){0.f, 0.f, 0.f, 0.f};
  // prologue: stage k0=0 into buf0
  *(bf16x8*)st0 = *(const bf16x8*)ag;
  __syncthreads();
  int buf = 0;
  for (int k0 = 0; k0 < K; k0 += 32, buf ^= 1) {
    bool more = (k0 + 32 < K);
    bf16x8 gn;
    if (more) gn = *(const bf16x8*)(ag + k0 + 32);  // prefetch A(k+1)
    bf16x8 b_h[4], b_l[4];
#pragma unroll
    for (int t = 0; t < 4; t++) {
      b_h[t] = *(const bf16x8*)(brh + (size_t)t * 16 * K + k0);
      b_l[t] = *(const bf16x8*)(brl + (size_t)t * 16 * K + k0);
    }
    const __bf16* rh = sAh[buf];
    const __bf16* rl = sAl[buf];
    bf16x8 a_h[2], a_l[2];
#pragma unroll
    for (int mt = 0; mt < 2; mt++) {
      int fi = ((mt * 4 + quad) * 16 + l16) * 8;
      a_h[mt] = *(const bf16x8*)(rh + fi);
      a_l[mt] = *(const bf16x8*)(rl + fi);
    }
#pragma unroll
    for (int t = 0; t < 4; t++) {
#pragma unroll
      for (int mt = 0; mt < 2; mt++) {
        acc[mt][t] = __builtin_amdgcn_mfma_f32_16x16x32_bf16(a_h[mt], b_h[t], acc[mt][t], 0, 0, 0);
        acc[mt][t] = __builtin_amdgcn_mfma_f32_16x16x32_bf16(a_h[mt], b_l[t], acc[mt][t], 0, 0, 0);
        acc[mt][t] = __builtin_amdgcn_mfma_f32_16x16x32_bf16(a_l[mt], b_h[t], acc[mt][t], 0, 0, 0);
      }
    }
    // write A(k+1) to the alternate buffer (its step-(k-1) readers were
    // fenced by the previous barrier); one barrier per step.
    if (more) *(bf16x8*)(buf ? st0 : st1) = gn;
    __syncthreads();
  }
#pragma unroll
  for (int mt = 0; mt < 2; mt++) {
#pragma unroll
    for (int t = 0; t < 4; t++) {
#pragma unroll
      for (int r = 0; r < 4; r++) {
        int m = m0 + mt * 16 + quad * 4 + r;
        if (m < M) {
          size_t o = (size_t)m * NcFull + col0 + t * 16 + l16;
          Ch[o] = (__bf16)acc[mt][t][r];
          Cf8[o] = f32_to_fp8(acc[mt][t][r]);
        }
      }
    }
  }
}

// ---------------- split-bf16 MFMA GEMM, no-LDS (layer 3) ----------------
template <int NT, int MT>
__global__ __launch_bounds__(256) void k_gemm_split(
    const __bf16* __restrict__ Ah, const __bf16* __restrict__ Al,
    const __bf16* __restrict__ BTh, const __bf16* __restrict__ BTl,
    __bf16* __restrict__ Ch, int M, int K, int NcFull) {
  int lane = threadIdx.x & 63;
  int wave = threadIdx.x >> 6;
  int quad = lane >> 4;
  int l16 = lane & 15;
  int m0 = blockIdx.y * (64 * MT) + wave * (16 * MT);
  int col0 = blockIdx.x * (NT * 16);
  const __bf16* arh[MT];
  const __bf16* arl[MT];
#pragma unroll
  for (int mt = 0; mt < MT; mt++) {
    int am = min(m0 + mt * 16 + l16, M - 1);
    arh[mt] = Ah + (size_t)am * K + quad * 8;
    arl[mt] = Al + (size_t)am * K + quad * 8;
  }
  const __bf16* brh = BTh + (size_t)(col0 + l16) * K + quad * 8;
  const __bf16* brl = BTl + (size_t)(col0 + l16) * K + quad * 8;
  f32x4 acc[MT][NT];
#pragma unroll
  for (int mt = 0; mt < MT; mt++)
#pragma unroll
    for (int t = 0; t < NT; t++) acc[mt][t] = (f32x4){0.f, 0.f, 0.f, 0.f};
  for (int k0 = 0; k0 < K; k0 += 32) {
    bf16x8 a_h[MT], a_l[MT], b_h[NT], b_l[NT];
#pragma unroll
    for (int mt = 0; mt < MT; mt++) {
      a_h[mt] = *(const bf16x8*)(arh[mt] + k0);
      a_l[mt] = *(const bf16x8*)(arl[mt] + k0);
    }
#pragma unroll
    for (int t = 0; t < NT; t++) {
      b_h[t] = *(const bf16x8*)(brh + (size_t)t * 16 * K + k0);
      b_l[t] = *(const bf16x8*)(brl + (size_t)t * 16 * K + k0);
    }
#pragma unroll
    for (int t = 0; t < NT; t++) {
#pragma unroll
      for (int mt = 0; mt < MT; mt++) {
        acc[mt][t] = __builtin_amdgcn_mfma_f32_16x16x32_bf16(a_h[mt], b_h[t], acc[mt][t], 0, 0, 0);
        acc[mt][t] = __builtin_amdgcn_mfma_f32_16x16x32_bf16(a_h[mt], b_l[t], acc[mt][t], 0, 0, 0);
        acc[mt][t] = __builtin_amdgcn_mfma_f32_16x16x32_bf16(a_l[mt], b_h[t], acc[mt][t], 0, 0, 0);
      }
    }
  }
#pragma unroll
  for (int mt = 0; mt < MT; mt++) {
#pragma unroll
    for (int t = 0; t < NT; t++) {
#pragma unroll
      for (int r = 0; r < 4; r++) {
        int m = m0 + mt * 16 + quad * 4 + r;
        if (m < M)
          Ch[(size_t)m * NcFull + col0 + t * 16 + l16] = (__bf16)acc[mt][t][r];
      }
    }
  }
}

// ---------------- attention dots (bf16-hi) ----------------
__global__ __launch_bounds__(256) void k_att(const __bf16* __restrict__ Hh,
                                             const float* __restrict__ attS,
                                             const float* __restrict__ attD,
                                             float* __restrict__ aS,
                                             float* __restrict__ aD, int NH, int H) {
  int idx = blockIdx.x * 256 + threadIdx.x;
  if (idx >= NH) return;
  int h = idx % H;
  const bf16x8* hv = (const bf16x8*)(Hh + (size_t)idx * 32);
  const float* sv = attS + h * 32;
  const float* dv = attD + h * 32;
  float ss = 0.f, dd = 0.f;
#pragma unroll
  for (int k = 0; k < 4; k++) {
    bf16x8 a = hv[k];
#pragma unroll
    for (int j = 0; j < 8; j++) {
      float v = (float)a[j];
      ss += v * sv[k * 8 + j];
      dd += v * dv[k * 8 + j];
    }
  }
  aS[idx] = ss;
  aD[idx] = dd;
}

// ---------------- dense edge-parallel alpha (R12) ----------------
__global__ __launch_bounds__(256) void k_edge_alpha8(
    const float* __restrict__ aS, const float* __restrict__ aD,
    const int* __restrict__ colsrc, const int* __restrict__ coldst,
    __bf16* __restrict__ ealpha, int M) {
  int e = blockIdx.x * 256 + threadIdx.x;
  if (e >= M) return;
  int src = colsrc[e];
  int dst = coldst[e];
  const float* ap = aS + (size_t)src * 8;
  const float* dp = aD + (size_t)dst * 8;
  bf16x8 ev;
#pragma unroll
  for (int h = 0; h < 8; h++) {
    float x = ap[h] + dp[h];
    x = (x > 0.f) ? x : 0.2f * x;
    ev[h] = (__bf16)__expf(x);
  }
  *(bf16x8*)(ealpha + (size_t)e * 8) = ev;
}

__global__ __launch_bounds__(256) void k_edge_alpha1(
    const float* __restrict__ aS, const float* __restrict__ aD,
    const int* __restrict__ colsrc, const int* __restrict__ coldst,
    __bf16* __restrict__ ealpha, int M) {
  int e = blockIdx.x * 256 + threadIdx.x;
  if (e >= M) return;
  float x = aS[colsrc[e]] + aD[coldst[e]];
  x = (x > 0.f) ? x : 0.2f * x;
  ealpha[e] = (__bf16)__expf(x);
}

// ---------------- GAT aggregation, H=8 (gather-only, R12) ----------------
__global__ __launch_bounds__(256) void k_gat_agg8(
    const unsigned char* __restrict__ Hf8, const int* __restrict__ rowptr,
    const int* __restrict__ colsrc, const __bf16* __restrict__ ealpha,
    const float* __restrict__ bias, __bf16* __restrict__ outh,
    __bf16* __restrict__ outl, int N) {
  int wid = (blockIdx.x * blockDim.x + threadIdx.x) >> 6;
  int lane = threadIdx.x & 63;
  if (wid >= N) return;
  int n = wid;
  int row0 = rowptr[n];
  int deg = rowptr[n + 1] - row0;
  int head = lane >> 3;

  f32x4 acc = (f32x4){0.f, 0.f, 0.f, 0.f};
  float den = 0.f;
  const __bf16* ea = ealpha;
  int i = 0;
  for (; i + 3 < deg; i += 4) {
    int sl = row0 + i;
    int s0 = colsrc[sl + 0];
    int s1 = colsrc[sl + 1];
    int s2 = colsrc[sl + 2];
    int s3 = colsrc[sl + 3];
    float w0 = (float)ea[(size_t)(sl + 0) * 8 + head];
    float w1 = (float)ea[(size_t)(sl + 1) * 8 + head];
    float w2 = (float)ea[(size_t)(sl + 2) * 8 + head];
    float w3 = (float)ea[(size_t)(sl + 3) * 8 + head];
    unsigned int p0 = *(const unsigned int*)(Hf8 + (size_t)s0 * 256 + lane * 4);
    unsigned int p1 = *(const unsigned int*)(Hf8 + (size_t)s1 * 256 + lane * 4);
    unsigned int p2 = *(const unsigned int*)(Hf8 + (size_t)s2 * 256 + lane * 4);
    unsigned int p3 = *(const unsigned int*)(Hf8 + (size_t)s3 * 256 + lane * 4);
    den += w0 + w1 + w2 + w3;
    fma_fp8x4(acc, w0, p0);
    fma_fp8x4(acc, w1, p1);
    fma_fp8x4(acc, w2, p2);
    fma_fp8x4(acc, w3, p3);
  }
  for (; i < deg; i++) {
    int sl = row0 + i;
    int s0 = colsrc[sl];
    float w0 = (float)ea[(size_t)sl * 8 + head];
    unsigned int p0 = *(const unsigned int*)(Hf8 + (size_t)s0 * 256 + lane * 4);
    den += w0;
    fma_fp8x4(acc, w0, p0);
  }
  float rsv = 1.f / den;  // deg >= 1 (self-loop), den > 0
  float4 bv = *(const float4*)(bias + lane * 4);
  bf16x4 hb, lb;
#pragma unroll
  for (int j = 0; j < 4; j++) {
    float v = acc[j] * rsv + ((const float*)&bv)[j];
    v = (v > 0.f) ? v : (__expf(v) - 1.f);  // ELU
    hb[j] = (__bf16)v;
    lb[j] = (__bf16)(v - (float)hb[j]);
  }
  *(bf16x4*)(outh + (size_t)n * 256 + lane * 4) = hb;
  *(bf16x4*)(outl + (size_t)n * 256 + lane * 4) = lb;
}

// ---------------- GAT aggregation, H=1 (layer 3, fp32 out, no ELU) ------
__global__ __launch_bounds__(256) void k_gat_agg1(
    const __bf16* __restrict__ Hh, const int* __restrict__ rowptr,
    const int* __restrict__ colsrc, const __bf16* __restrict__ ealpha,
    const float* __restrict__ bias, float* __restrict__ out, int N) {
  int wid = (blockIdx.x * blockDim.x + threadIdx.x) >> 6;
  int lane = threadIdx.x & 63;
  if (wid >= N) return;
  int n = wid;
  int row0 = rowptr[n];
  int deg = rowptr[n + 1] - row0;
  int eo = lane >> 3;
  int cl = lane & 7;
  f32x4 acc = (f32x4){0.f, 0.f, 0.f, 0.f};
  float den = 0.f;
  for (int i = eo; i < deg; i += 8) {
    int slot = row0 + i;
    int src = colsrc[slot];
    float w = (float)ealpha[slot];
    den += w;
    bf16x4 hv = *(const bf16x4*)(Hh + (size_t)src * 32 + cl * 4);
#pragma unroll
    for (int j = 0; j < 4; j++) acc[j] += w * (float)hv[j];
  }
#pragma unroll
  for (int off = 8; off < 64; off <<= 1) {
#pragma unroll
    for (int j = 0; j < 4; j++) acc[j] += __shfl_xor(acc[j], off, 64);
    den += __shfl_xor(den, off, 64);
  }
  if (eo == 0) {
    float rsv = 1.f / den;
#pragma unroll
    for (int j = 0; j < 4; j++)
      out[(size_t)n * 32 + cl * 4 + j] = acc[j] * rsv + bias[cl * 4 + j];
  }
}

// ---------------- fused mean-pool + linear ----------------
__global__ __launch_bounds__(256) void k_pool_final(
    const float* __restrict__ h, const int* __restrict__ batch,
    const float* __restrict__ linW, const float* __restrict__ linb,
    float* __restrict__ out, int N) {
  __shared__ float sh[256];
  int g = blockIdx.x;
  int tid = threadIdx.x;
  int grp = tid >> 5, c = tid & 31;
  int lo = 0, hi = N;
  while (lo < hi) { int mid = (lo + hi) >> 1; if (batch[mid] < g) lo = mid + 1; else hi = mid; }
  int start = lo;
  hi = N;
  while (lo < hi) { int mid = (lo + hi) >> 1; if (batch[mid] < g + 1) lo = mid + 1; else hi = mid; }
  int end = lo;
  float acc = 0.f;
  for (int n = start + grp; n < end; n += 8) acc += h[(size_t)n * 32 + c];
  sh[tid] = acc;
  __syncthreads();
  if (tid < 32) {
    float s = 0.f;
#pragma unroll
    for (int j = 0; j < 8; j++) s += sh[j * 32 + tid];
    float v = s * linW[tid];
#pragma unroll
    for (int off = 16; off > 0; off >>= 1) v += __shfl_xor(v, off, 64);
    if (tid == 0) {
      float cnt = (float)(end - start);
      out[g] = v / fmaxf(cnt, 1.f) + linb[0];
    }
  }
}

extern "C" void kernel_launch(void* const* d_in, const int* in_sizes, int n_in,
                              void* d_out, int out_size, void* d_ws, size_t ws_size,
                              hipStream_t stream) {
  const float* x = (const float*)d_in[0];
  const int* ei = (const int*)d_in[1];
  const int* batch = (const int*)d_in[2];
  const float* W1 = (const float*)d_in[3];
  const float* as1 = (const float*)d_in[4];
  const float* ad1 = (const float*)d_in[5];
  const float* b1 = (const float*)d_in[6];
  const float* W2 = (const float*)d_in[7];
  const float* as2 = (const float*)d_in[8];
  const float* ad2 = (const float*)d_in[9];
  const float* b2 = (const float*)d_in[10];
  const float* W3 = (const float*)d_in[11];
  const float* as3 = (const float*)d_in[12];
  const float* ad3 = (const float*)d_in[13];
  const float* b3 = (const float*)d_in[14];
  const float* linW = (const float*)d_in[15];
  const float* linb = (const float*)d_in[16];

  const int N = in_sizes[0] / 256;
  const int E = in_sizes[1] / 2;
  const int NUM_GRAPHS = 64;
  float* out = (float*)d_out;

  char* ws = (char*)d_ws;
  size_t off = 0;
  auto alloc = [&](size_t bytes) -> void* {
    void* p = ws + off;
    off += (bytes + 255) & ~(size_t)255;
    return p;
  };
  __bf16* Hh = (__bf16*)alloc((size_t)N * 256 * 2);  // GEMM h out (bf16-hi)
  unsigned char* Hf8 = (unsigned char*)alloc((size_t)N * 256);  // fp8 copy
  __bf16* Ah = (__bf16*)alloc((size_t)N * 256 * 2);  // GEMM A in (hi)
  __bf16* Al = (__bf16*)alloc((size_t)N * 256 * 2);  //           (lo)
  __bf16* ealpha = (__bf16*)alloc((size_t)(E + N) * 8 * 2);  // per-edge exps
  float* aS = (float*)alloc((size_t)N * 8 * 4);
  float* aD = (float*)alloc((size_t)N * 8 * 4);
  int* deg = (int*)alloc((size_t)N * 4);
  int* rowptr = (int*)alloc((size_t)(N + 1) * 4);
  int* cursor = (int*)alloc((size_t)(N + 1) * 4);
  int* colsrc = (int*)alloc((size_t)(E + N) * 4);
  int* coldst = (int*)alloc((size_t)(E + N) * 4);
  int* blockSums = (int*)alloc(256 * 4);
  int* blockOffs = (int*)alloc(256 * 4);
  __bf16* WT1h = (__bf16*)alloc(256 * 256 * 2);
  __bf16* WT1l = (__bf16*)alloc(256 * 256 * 2);
  __bf16* WT2h = (__bf16*)alloc(256 * 256 * 2);
  __bf16* WT2l = (__bf16*)alloc(256 * 256 * 2);
  __bf16* WT3h = (__bf16*)alloc(32 * 256 * 2);
  __bf16* WT3l = (__bf16*)alloc(32 * 256 * 2);
  // h3agg reuses Ah (GEMM3 already consumed Ah/Al when agg3 writes)
  float* h3agg = (float*)Ah;

  // --- preps: x split + W transposes/splits + CSR build ---
  k_split<<<(N * 64 + 255) / 256, 256, 0, stream>>>(x, Ah, Al, N * 64);
  k_wprep<<<(256 * 256 + 255) / 256, 256, 0, stream>>>(W1, WT1h, WT1l, 256, 256);
  k_wprep<<<(256 * 256 + 255) / 256, 256, 0, stream>>>(W2, WT2h, WT2l, 256, 256);
  k_wprep<<<(256 * 32 + 255) / 256, 256, 0, stream>>>(W3, WT3h, WT3l, 256, 32);
  k_init_deg<<<(N + 255) / 256, 256, 0, stream>>>(deg, N);
  k_count_deg<<<(E + 255) / 256, 256, 0, stream>>>(ei, E, deg);
  const int nb = (N + 256 * SCAN_CH - 1) / (256 * SCAN_CH);  // 49 <= 256
  k_scan_partial<<<nb, 256, 0, stream>>>(deg, blockSums, N);
  k_scan_blocksums<<<1, 256, 0, stream>>>(blockSums, blockOffs, rowptr, nb, N);
  k_scan_final<<<nb, 256, 0, stream>>>(deg, blockOffs, rowptr, cursor, N);
  k_scatter<<<(E + N + 255) / 256, 256, 0, stream>>>(ei, E, N, cursor, colsrc, coldst);

  const int aggBlocks = (N + 3) / 4;
  const int gemmBlocks = (N + 31) / 32;  // 32 rows/block, full 256-col width
  const int M = E + N;
  const int edgeBlocks = (M + 255) / 256;
  dim3 g3(1, (N + 63) / 64);

  // --- layer 1 ---
  k_gemm_lds<<<gemmBlocks, 256, 0, stream>>>(Ah, Al, WT1h, WT1l, Hh, Hf8, N, 256);
  k_att<<<(N * 8 + 255) / 256, 256, 0, stream>>>(Hh, as1, ad1, aS, aD, N * 8, 8);
  k_edge_alpha8<<<edgeBlocks, 256, 0, stream>>>(aS, aD, colsrc, coldst, ealpha, M);
  k_gat_agg8<<<aggBlocks, 256, 0, stream>>>(Hf8, rowptr, colsrc, ealpha, b1,
                                            Ah, Al, N);
  // --- layer 2 ---
  k_gemm_lds<<<gemmBlocks, 256, 0, stream>>>(Ah, Al, WT2h, WT2l, Hh, Hf8, N, 256);
  k_att<<<(N * 8 + 255) / 256, 256, 0, stream>>>(Hh, as2, ad2, aS, aD, N * 8, 8);
  k_edge_alpha8<<<edgeBlocks, 256, 0, stream>>>(aS, aD, colsrc, coldst, ealpha, M);
  k_gat_agg8<<<aggBlocks, 256, 0, stream>>>(Hf8, rowptr, colsrc, ealpha, b2,
                                            Ah, Al, N);
  // --- layer 3 (H=1, bf16 gather) ---
  k_gemm_split<2, 1><<<g3, 256, 0, stream>>>(Ah, Al, WT3h, WT3l, Hh, N, 256, 32);
  k_att<<<(N + 255) / 256, 256, 0, stream>>>(Hh, as3, ad3, aS, aD, N, 1);
  k_edge_alpha1<<<edgeBlocks, 256, 0, stream>>>(aS, aD, colsrc, coldst, ealpha, M);
  k_gat_agg1<<<aggBlocks, 256, 0, stream>>>(Hh, rowptr, colsrc, ealpha, b3,
                                            h3agg, N);
  // --- pool + final ---
  k_pool_final<<<NUM_GRAPHS, 256, 0, stream>>>(h3agg, batch, linW, linb, out, N);
}

// Round 14
// 512.127 us; speedup vs baseline: 1.1127x; 1.1127x over previous
//
#include <hip/hip_runtime.h>
#include <hip/hip_fp8.h>
#include <math.h>

// ---------------------------------------------------------------------------
// GATClassifier on MI355X.
//   1. CSR build over dst (histogram -> 3-phase scan -> scatter w/ colsrc+coldst)
//   2. Per layer: MFMA GEMM h = (Ah+Al) @ bf16(B) — A split-bf16 (exact),
//      B plain bf16 (R14: h-err 1.6e-3, ~15x below the fp8-gather term whose
//      measured output impact is 2.4e-4; halves B-bytes, the binding GEMM
//      resource per R13's failed 32-row experiment). LDS-staged A (read-once),
//      DOUBLE-buffered + 1-step prefetch + 1 barrier/k-step, 64 rows/block.
//      h stored bf16-hi + fp8 copy; att dots from bf16; dense edge-parallel
//      exp(leaky()) -> bf16 ealpha; agg = gather-only serial loop with
//      per-lane den accumulation (no shuffles).
//   3. Fused mean-pool + 32->1 linear (batch sorted -> binary search)
// History: R2 pool 383. R3 SGEMM 158x2. R4 agg 155x2. R5 gemm 140x2. R6 agg
// 131x2. R7 scan 111. R8 agg 87x2. R9 gemm 89x2. R10 agg 80x2. R11 agg 71x2.
// R12 gemm 57x2 (barrier drain). R13 32-row dbuf REGRESSED (68x2: halved
// MFMA:B ratio) -> R14 64-row dbuf + drop Bl.
// NOTE: edge_index / batch are int32.
// ---------------------------------------------------------------------------

typedef __attribute__((ext_vector_type(8))) __bf16 bf16x8;
typedef __attribute__((ext_vector_type(4))) __bf16 bf16x4;
typedef __attribute__((ext_vector_type(4))) float f32x4;
typedef __attribute__((ext_vector_type(2))) float f32x2;

#define SCAN_CH 4  // elements per thread in the device-wide scan

__device__ inline unsigned char f32_to_fp8(float f) {
  __hip_fp8_e4m3 v(f);
  return (unsigned char)v.__x;
}
__device__ inline float fp8_to_f32(unsigned char u) {
  __hip_fp8_e4m3 v;
  v.__x = (__hip_fp8_storage_t)u;
  return (float)v;
}

// Decode 4 packed fp8-e4m3 bytes -> 4 floats, accumulate w * val into acc.
__device__ inline void fma_fp8x4(f32x4& acc, float w, unsigned int packed) {
#if defined(__has_builtin) && __has_builtin(__builtin_amdgcn_cvt_pk_f32_fp8)
  f32x2 lo = __builtin_amdgcn_cvt_pk_f32_fp8((int)packed, false);  // bytes 0,1
  f32x2 hi = __builtin_amdgcn_cvt_pk_f32_fp8((int)packed, true);   // bytes 2,3
  acc[0] += w * lo[0];
  acc[1] += w * lo[1];
  acc[2] += w * hi[0];
  acc[3] += w * hi[1];
#else
  acc[0] += w * fp8_to_f32((unsigned char)(packed & 0xff));
  acc[1] += w * fp8_to_f32((unsigned char)((packed >> 8) & 0xff));
  acc[2] += w * fp8_to_f32((unsigned char)((packed >> 16) & 0xff));
  acc[3] += w * fp8_to_f32((unsigned char)(packed >> 24));
#endif
}

// ---------------- CSR build ----------------
__global__ __launch_bounds__(256) void k_init_deg(int* deg, int N) {
  int n = blockIdx.x * 256 + threadIdx.x;
  if (n < N) deg[n] = 1;  // self-loop
}

__global__ __launch_bounds__(256) void k_count_deg(const int* __restrict__ ei,
                                                   int E, int* deg) {
  int e = blockIdx.x * 256 + threadIdx.x;
  if (e < E) atomicAdd(&deg[ei[E + e]], 1);
}

// --- 3-phase exclusive scan (R8: old single-block scan was 111us on 1 CU) ---
__global__ __launch_bounds__(256) void k_scan_partial(const int* __restrict__ deg,
                                                      int* __restrict__ blockSums,
                                                      int N) {
  __shared__ int sh[256];
  int t = threadIdx.x, b = blockIdx.x;
  int base = (b * 256 + t) * SCAN_CH;
  int s = 0;
#pragma unroll
  for (int j = 0; j < SCAN_CH; j++) {
    int idx = base + j;
    if (idx < N) s += deg[idx];
  }
  sh[t] = s;
  __syncthreads();
  for (int off = 128; off > 0; off >>= 1) {
    if (t < off) sh[t] += sh[t + off];
    __syncthreads();
  }
  if (t == 0) blockSums[b] = sh[0];
}

__global__ __launch_bounds__(256) void k_scan_blocksums(
    const int* __restrict__ blockSums, int* __restrict__ blockOffs,
    int* __restrict__ rowptr, int nb, int N) {
  __shared__ int sh[256];
  int t = threadIdx.x;
  int v = (t < nb) ? blockSums[t] : 0;
  sh[t] = v;
  __syncthreads();
  for (int off = 1; off < 256; off <<= 1) {
    int u = (t >= off) ? sh[t - off] : 0;
    __syncthreads();
    sh[t] += u;
    __syncthreads();
  }
  if (t < nb) blockOffs[t] = sh[t] - v;  // exclusive
  if (t == nb - 1) rowptr[N] = sh[t];    // total
}

__global__ __launch_bounds__(256) void k_scan_final(const int* __restrict__ deg,
                                                    const int* __restrict__ blockOffs,
                                                    int* __restrict__ rowptr,
                                                    int* __restrict__ cursor, int N) {
  __shared__ int sh[256];
  int t = threadIdx.x, b = blockIdx.x;
  int base = (b * 256 + t) * SCAN_CH;
  int vals[SCAN_CH];
  int s = 0;
#pragma unroll
  for (int j = 0; j < SCAN_CH; j++) {
    int idx = base + j;
    vals[j] = (idx < N) ? deg[idx] : 0;
    s += vals[j];
  }
  sh[t] = s;
  __syncthreads();
  for (int off = 1; off < 256; off <<= 1) {
    int u = (t >= off) ? sh[t - off] : 0;
    __syncthreads();
    sh[t] += u;
    __syncthreads();
  }
  int run = blockOffs[b] + sh[t] - s;  // exclusive prefix for this thread
#pragma unroll
  for (int j = 0; j < SCAN_CH; j++) {
    int idx = base + j;
    if (idx < N) {
      rowptr[idx] = run;
      cursor[idx] = run;
      run += vals[j];
    }
  }
}

__global__ __launch_bounds__(256) void k_scatter(const int* __restrict__ ei,
                                                 int E, int N, int* cursor,
                                                 int* __restrict__ colsrc,
                                                 int* __restrict__ coldst) {
  int i = blockIdx.x * 256 + threadIdx.x;
  if (i < E) {
    int s = ei[i];
    int d = ei[E + i];
    int pos = atomicAdd(&cursor[d], 1);
    colsrc[pos] = s;
    coldst[pos] = d;
  } else if (i < E + N) {
    int nn = i - E;
    int pos = atomicAdd(&cursor[nn], 1);
    colsrc[pos] = nn;  // self loop
    coldst[pos] = nn;
  }
}

// ---------------- split-cast preps ----------------
__global__ __launch_bounds__(256) void k_split(const float* __restrict__ in,
                                               __bf16* __restrict__ oh,
                                               __bf16* __restrict__ ol, int n4) {
  int i = blockIdx.x * 256 + threadIdx.x;
  if (i >= n4) return;
  float4 v = ((const float4*)in)[i];
  bf16x4 h, l;
  h[0] = (__bf16)v.x; l[0] = (__bf16)(v.x - (float)h[0]);
  h[1] = (__bf16)v.y; l[1] = (__bf16)(v.y - (float)h[1]);
  h[2] = (__bf16)v.z; l[2] = (__bf16)(v.z - (float)h[2]);
  h[3] = (__bf16)v.w; l[3] = (__bf16)(v.w - (float)h[3]);
  ((bf16x4*)oh)[i] = h;
  ((bf16x4*)ol)[i] = l;
}

// W [K][Nc] fp32 -> WT [Nc][K] plain bf16 (R14: Bl dropped — B-bytes were
// the binding GEMM resource; h-error 1.6e-3 washes to ~2e-5 at output).
__global__ __launch_bounds__(256) void k_wprep(const float* __restrict__ W,
                                               __bf16* __restrict__ WTh,
                                               int K, int Nc) {
  int i = blockIdx.x * 256 + threadIdx.x;  // i = n*K + k
  if (i >= K * Nc) return;
  int n = i / K, k = i - n * K;
  WTh[i] = (__bf16)W[k * Nc + n];
}

// ---------------- LDS-shared MFMA GEMM (layers 1/2, R14) -----------------
// C = (Ah+Al) @ Bh. Block = 64 rows x 256 cols (782 blocks). A-tile
// (64x32 hi+lo, 8KB) in a DOUBLE-BUFFERED LDS stage: A(k+1) global-loaded
// at the top of step k, written to the alternate buffer after the MFMAs,
// ONE barrier per step (R12's 2-barrier version drained the HBM load every
// step; R13's 32-row version halved the MFMA:B ratio — both fixed here).
// Per k-step per wave: 4 B-loads + 32 MFMAs. Staging fragment-order.
// mfma_f32_16x16x32_bf16 (m89-verified): A: m=lane&15,k=quad*8+j;
// B: n=lane&15,k=quad*8+j (from WT); C/D: row=quad*4+reg, col=lane&15.
__global__ __launch_bounds__(256) void k_gemm_lds(
    const __bf16* __restrict__ Ah, const __bf16* __restrict__ Al,
    const __bf16* __restrict__ BTh,
    __bf16* __restrict__ Ch, unsigned char* __restrict__ Cf8, int M, int K) {
  constexpr int NcFull = 256;
  __shared__ __bf16 sAh[2][2048];  // [buf][(mt*4+kq)*16+l16][8]
  __shared__ __bf16 sAl[2][2048];
  int tid = threadIdx.x;
  int lane = tid & 63, wave = tid >> 6;
  int quad = lane >> 4, l16 = lane & 15;
  int m0 = blockIdx.x * 64;
  int col0 = wave * 64;
  // staging map: thread t -> row sr = t>>2 (0..63), k-quad skq = t&3
  int sr = tid >> 2, skq = tid & 3;
  int slot8 = (((sr >> 4) * 4 + skq) * 16 + (sr & 15)) * 8;
  int arow = min(m0 + sr, M - 1);  // clamp: rows >= M never stored
  const __bf16* agh = Ah + (size_t)arow * K + skq * 8;
  const __bf16* agl = Al + (size_t)arow * K + skq * 8;
  const __bf16* brh = BTh + (size_t)(col0 + l16) * K + quad * 8;
  f32x4 acc[4][4];  // [mt][nt]
#pragma unroll
  for (int mt = 0; mt < 4; mt++)
#pragma unroll
    for (int t = 0; t < 4; t++) acc[mt][t] = (f32x4){0.f, 0.f, 0.f, 0.f};
  // prologue: stage k0=0 into buf0
  *(bf16x8*)(sAh[0] + slot8) = *(const bf16x8*)agh;
  *(bf16x8*)(sAl[0] + slot8) = *(const bf16x8*)agl;
  __syncthreads();
  int buf = 0;
  for (int k0 = 0; k0 < K; k0 += 32, buf ^= 1) {
    bool more = (k0 + 32 < K);
    bf16x8 gh, gl;
    if (more) {  // prefetch A(k+1); has the whole compute phase to land
      gh = *(const bf16x8*)(agh + k0 + 32);
      gl = *(const bf16x8*)(agl + k0 + 32);
    }
    bf16x8 b_h[4];
#pragma unroll
    for (int t = 0; t < 4; t++)
      b_h[t] = *(const bf16x8*)(brh + (size_t)t * 16 * K + k0);
    const __bf16* rh = sAh[buf];
    const __bf16* rl = sAl[buf];
    bf16x8 a_h[4], a_l[4];
#pragma unroll
    for (int mt = 0; mt < 4; mt++) {
      int fi = ((mt * 4 + quad) * 16 + l16) * 8;
      a_h[mt] = *(const bf16x8*)(rh + fi);
      a_l[mt] = *(const bf16x8*)(rl + fi);
    }
#pragma unroll
    for (int t = 0; t < 4; t++) {
#pragma unroll
      for (int mt = 0; mt < 4; mt++) {
        acc[mt][t] = __builtin_amdgcn_mfma_f32_16x16x32_bf16(a_h[mt], b_h[t], acc[mt][t], 0, 0, 0);
        acc[mt][t] = __builtin_amdgcn_mfma_f32_16x16x32_bf16(a_l[mt], b_h[t], acc[mt][t], 0, 0, 0);
      }
    }
    // write A(k+1) to the alternate buffer (its readers were fenced by the
    // previous barrier); single barrier per step.
    if (more) {
      *(bf16x8*)(sAh[buf ^ 1] + slot8) = gh;
      *(bf16x8*)(sAl[buf ^ 1] + slot8) = gl;
    }
    __syncthreads();
  }
#pragma unroll
  for (int mt = 0; mt < 4; mt++) {
#pragma unroll
    for (int t = 0; t < 4; t++) {
#pragma unroll
      for (int r = 0; r < 4; r++) {
        int m = m0 + mt * 16 + quad * 4 + r;
        if (m < M) {
          size_t o = (size_t)m * NcFull + col0 + t * 16 + l16;
          Ch[o] = (__bf16)acc[mt][t][r];
          Cf8[o] = f32_to_fp8(acc[mt][t][r]);
        }
      }
    }
  }
}

// ---------------- MFMA GEMM, no-LDS (layer 3): (Ah+Al) @ Bh -------------
template <int NT, int MT>
__global__ __launch_bounds__(256) void k_gemm_split(
    const __bf16* __restrict__ Ah, const __bf16* __restrict__ Al,
    const __bf16* __restrict__ BTh,
    __bf16* __restrict__ Ch, int M, int K, int NcFull) {
  int lane = threadIdx.x & 63;
  int wave = threadIdx.x >> 6;
  int quad = lane >> 4;
  int l16 = lane & 15;
  int m0 = blockIdx.y * (64 * MT) + wave * (16 * MT);
  int col0 = blockIdx.x * (NT * 16);
  const __bf16* arh[MT];
  const __bf16* arl[MT];
#pragma unroll
  for (int mt = 0; mt < MT; mt++) {
    int am = min(m0 + mt * 16 + l16, M - 1);
    arh[mt] = Ah + (size_t)am * K + quad * 8;
    arl[mt] = Al + (size_t)am * K + quad * 8;
  }
  const __bf16* brh = BTh + (size_t)(col0 + l16) * K + quad * 8;
  f32x4 acc[MT][NT];
#pragma unroll
  for (int mt = 0; mt < MT; mt++)
#pragma unroll
    for (int t = 0; t < NT; t++) acc[mt][t] = (f32x4){0.f, 0.f, 0.f, 0.f};
  for (int k0 = 0; k0 < K; k0 += 32) {
    bf16x8 a_h[MT], a_l[MT], b_h[NT];
#pragma unroll
    for (int mt = 0; mt < MT; mt++) {
      a_h[mt] = *(const bf16x8*)(arh[mt] + k0);
      a_l[mt] = *(const bf16x8*)(arl[mt] + k0);
    }
#pragma unroll
    for (int t = 0; t < NT; t++)
      b_h[t] = *(const bf16x8*)(brh + (size_t)t * 16 * K + k0);
#pragma unroll
    for (int t = 0; t < NT; t++) {
#pragma unroll
      for (int mt = 0; mt < MT; mt++) {
        acc[mt][t] = __builtin_amdgcn_mfma_f32_16x16x32_bf16(a_h[mt], b_h[t], acc[mt][t], 0, 0, 0);
        acc[mt][t] = __builtin_amdgcn_mfma_f32_16x16x32_bf16(a_l[mt], b_h[t], acc[mt][t], 0, 0, 0);
      }
    }
  }
#pragma unroll
  for (int mt = 0; mt < MT; mt++) {
#pragma unroll
    for (int t = 0; t < NT; t++) {
#pragma unroll
      for (int r = 0; r < 4; r++) {
        int m = m0 + mt * 16 + quad * 4 + r;
        if (m < M)
          Ch[(size_t)m * NcFull + col0 + t * 16 + l16] = (__bf16)acc[mt][t][r];
      }
    }
  }
}

// ---------------- attention dots (bf16-hi) ----------------
__global__ __launch_bounds__(256) void k_att(const __bf16* __restrict__ Hh,
                                             const float* __restrict__ attS,
                                             const float* __restrict__ attD,
                                             float* __restrict__ aS,
                                             float* __restrict__ aD, int NH, int H) {
  int idx = blockIdx.x * 256 + threadIdx.x;
  if (idx >= NH) return;
  int h = idx % H;
  const bf16x8* hv = (const bf16x8*)(Hh + (size_t)idx * 32);
  const float* sv = attS + h * 32;
  const float* dv = attD + h * 32;
  float ss = 0.f, dd = 0.f;
#pragma unroll
  for (int k = 0; k < 4; k++) {
    bf16x8 a = hv[k];
#pragma unroll
    for (int j = 0; j < 8; j++) {
      float v = (float)a[j];
      ss += v * sv[k * 8 + j];
      dd += v * dv[k * 8 + j];
    }
  }
  aS[idx] = ss;
  aD[idx] = dd;
}

// ---------------- dense edge-parallel alpha (R12) ----------------
__global__ __launch_bounds__(256) void k_edge_alpha8(
    const float* __restrict__ aS, const float* __restrict__ aD,
    const int* __restrict__ colsrc, const int* __restrict__ coldst,
    __bf16* __restrict__ ealpha, int M) {
  int e = blockIdx.x * 256 + threadIdx.x;
  if (e >= M) return;
  int src = colsrc[e];
  int dst = coldst[e];
  const float* ap = aS + (size_t)src * 8;
  const float* dp = aD + (size_t)dst * 8;
  bf16x8 ev;
#pragma unroll
  for (int h = 0; h < 8; h++) {
    float x = ap[h] + dp[h];
    x = (x > 0.f) ? x : 0.2f * x;
    ev[h] = (__bf16)__expf(x);
  }
  *(bf16x8*)(ealpha + (size_t)e * 8) = ev;
}

__global__ __launch_bounds__(256) void k_edge_alpha1(
    const float* __restrict__ aS, const float* __restrict__ aD,
    const int* __restrict__ colsrc, const int* __restrict__ coldst,
    __bf16* __restrict__ ealpha, int M) {
  int e = blockIdx.x * 256 + threadIdx.x;
  if (e >= M) return;
  float x = aS[colsrc[e]] + aD[coldst[e]];
  x = (x > 0.f) ? x : 0.2f * x;
  ealpha[e] = (__bf16)__expf(x);
}

// ---------------- GAT aggregation, H=8 (gather-only, R12) ----------------
__global__ __launch_bounds__(256) void k_gat_agg8(
    const unsigned char* __restrict__ Hf8, const int* __restrict__ rowptr,
    const int* __restrict__ colsrc, const __bf16* __restrict__ ealpha,
    const float* __restrict__ bias, __bf16* __restrict__ outh,
    __bf16* __restrict__ outl, int N) {
  int wid = (blockIdx.x * blockDim.x + threadIdx.x) >> 6;
  int lane = threadIdx.x & 63;
  if (wid >= N) return;
  int n = wid;
  int row0 = rowptr[n];
  int deg = rowptr[n + 1] - row0;
  int head = lane >> 3;

  f32x4 acc = (f32x4){0.f, 0.f, 0.f, 0.f};
  float den = 0.f;
  const __bf16* ea = ealpha;
  int i = 0;
  for (; i + 3 < deg; i += 4) {
    int sl = row0 + i;
    int s0 = colsrc[sl + 0];
    int s1 = colsrc[sl + 1];
    int s2 = colsrc[sl + 2];
    int s3 = colsrc[sl + 3];
    float w0 = (float)ea[(size_t)(sl + 0) * 8 + head];
    float w1 = (float)ea[(size_t)(sl + 1) * 8 + head];
    float w2 = (float)ea[(size_t)(sl + 2) * 8 + head];
    float w3 = (float)ea[(size_t)(sl + 3) * 8 + head];
    unsigned int p0 = *(const unsigned int*)(Hf8 + (size_t)s0 * 256 + lane * 4);
    unsigned int p1 = *(const unsigned int*)(Hf8 + (size_t)s1 * 256 + lane * 4);
    unsigned int p2 = *(const unsigned int*)(Hf8 + (size_t)s2 * 256 + lane * 4);
    unsigned int p3 = *(const unsigned int*)(Hf8 + (size_t)s3 * 256 + lane * 4);
    den += w0 + w1 + w2 + w3;
    fma_fp8x4(acc, w0, p0);
    fma_fp8x4(acc, w1, p1);
    fma_fp8x4(acc, w2, p2);
    fma_fp8x4(acc, w3, p3);
  }
  for (; i < deg; i++) {
    int sl = row0 + i;
    int s0 = colsrc[sl];
    float w0 = (float)ea[(size_t)sl * 8 + head];
    unsigned int p0 = *(const unsigned int*)(Hf8 + (size_t)s0 * 256 + lane * 4);
    den += w0;
    fma_fp8x4(acc, w0, p0);
  }
  float rsv = 1.f / den;  // deg >= 1 (self-loop), den > 0
  float4 bv = *(const float4*)(bias + lane * 4);
  bf16x4 hb, lb;
#pragma unroll
  for (int j = 0; j < 4; j++) {
    float v = acc[j] * rsv + ((const float*)&bv)[j];
    v = (v > 0.f) ? v : (__expf(v) - 1.f);  // ELU
    hb[j] = (__bf16)v;
    lb[j] = (__bf16)(v - (float)hb[j]);
  }
  *(bf16x4*)(outh + (size_t)n * 256 + lane * 4) = hb;
  *(bf16x4*)(outl + (size_t)n * 256 + lane * 4) = lb;
}

// ---------------- GAT aggregation, H=1 (layer 3, fp32 out, no ELU) ------
__global__ __launch_bounds__(256) void k_gat_agg1(
    const __bf16* __restrict__ Hh, const int* __restrict__ rowptr,
    const int* __restrict__ colsrc, const __bf16* __restrict__ ealpha,
    const float* __restrict__ bias, float* __restrict__ out, int N) {
  int wid = (blockIdx.x * blockDim.x + threadIdx.x) >> 6;
  int lane = threadIdx.x & 63;
  if (wid >= N) return;
  int n = wid;
  int row0 = rowptr[n];
  int deg = rowptr[n + 1] - row0;
  int eo = lane >> 3;
  int cl = lane & 7;
  f32x4 acc = (f32x4){0.f, 0.f, 0.f, 0.f};
  float den = 0.f;
  for (int i = eo; i < deg; i += 8) {
    int slot = row0 + i;
    int src = colsrc[slot];
    float w = (float)ealpha[slot];
    den += w;
    bf16x4 hv = *(const bf16x4*)(Hh + (size_t)src * 32 + cl * 4);
#pragma unroll
    for (int j = 0; j < 4; j++) acc[j] += w * (float)hv[j];
  }
#pragma unroll
  for (int off = 8; off < 64; off <<= 1) {
#pragma unroll
    for (int j = 0; j < 4; j++) acc[j] += __shfl_xor(acc[j], off, 64);
    den += __shfl_xor(den, off, 64);
  }
  if (eo == 0) {
    float rsv = 1.f / den;
#pragma unroll
    for (int j = 0; j < 4; j++)
      out[(size_t)n * 32 + cl * 4 + j] = acc[j] * rsv + bias[cl * 4 + j];
  }
}

// ---------------- fused mean-pool + linear ----------------
__global__ __launch_bounds__(256) void k_pool_final(
    const float* __restrict__ h, const int* __restrict__ batch,
    const float* __restrict__ linW, const float* __restrict__ linb,
    float* __restrict__ out, int N) {
  __shared__ float sh[256];
  int g = blockIdx.x;
  int tid = threadIdx.x;
  int grp = tid >> 5, c = tid & 31;
  int lo = 0, hi = N;
  while (lo < hi) { int mid = (lo + hi) >> 1; if (batch[mid] < g) lo = mid + 1; else hi = mid; }
  int start = lo;
  hi = N;
  while (lo < hi) { int mid = (lo + hi) >> 1; if (batch[mid] < g + 1) lo = mid + 1; else hi = mid; }
  int end = lo;
  float acc = 0.f;
  for (int n = start + grp; n < end; n += 8) acc += h[(size_t)n * 32 + c];
  sh[tid] = acc;
  __syncthreads();
  if (tid < 32) {
    float s = 0.f;
#pragma unroll
    for (int j = 0; j < 8; j++) s += sh[j * 32 + tid];
    float v = s * linW[tid];
#pragma unroll
    for (int off = 16; off > 0; off >>= 1) v += __shfl_xor(v, off, 64);
    if (tid == 0) {
      float cnt = (float)(end - start);
      out[g] = v / fmaxf(cnt, 1.f) + linb[0];
    }
  }
}

extern "C" void kernel_launch(void* const* d_in, const int* in_sizes, int n_in,
                              void* d_out, int out_size, void* d_ws, size_t ws_size,
                              hipStream_t stream) {
  const float* x = (const float*)d_in[0];
  const int* ei = (const int*)d_in[1];
  const int* batch = (const int*)d_in[2];
  const float* W1 = (const float*)d_in[3];
  const float* as1 = (const float*)d_in[4];
  const float* ad1 = (const float*)d_in[5];
  const float* b1 = (const float*)d_in[6];
  const float* W2 = (const float*)d_in[7];
  const float* as2 = (const float*)d_in[8];
  const float* ad2 = (const float*)d_in[9];
  const float* b2 = (const float*)d_in[10];
  const float* W3 = (const float*)d_in[11];
  const float* as3 = (const float*)d_in[12];
  const float* ad3 = (const float*)d_in[13];
  const float* b3 = (const float*)d_in[14];
  const float* linW = (const float*)d_in[15];
  const float* linb = (const float*)d_in[16];

  const int N = in_sizes[0] / 256;
  const int E = in_sizes[1] / 2;
  const int NUM_GRAPHS = 64;
  float* out = (float*)d_out;

  char* ws = (char*)d_ws;
  size_t off = 0;
  auto alloc = [&](size_t bytes) -> void* {
    void* p = ws + off;
    off += (bytes + 255) & ~(size_t)255;
    return p;
  };
  __bf16* Hh = (__bf16*)alloc((size_t)N * 256 * 2);  // GEMM h out (bf16-hi)
  unsigned char* Hf8 = (unsigned char*)alloc((size_t)N * 256);  // fp8 copy
  __bf16* Ah = (__bf16*)alloc((size_t)N * 256 * 2);  // GEMM A in (hi)
  __bf16* Al = (__bf16*)alloc((size_t)N * 256 * 2);  //           (lo)
  __bf16* ealpha = (__bf16*)alloc((size_t)(E + N) * 8 * 2);  // per-edge exps
  float* aS = (float*)alloc((size_t)N * 8 * 4);
  float* aD = (float*)alloc((size_t)N * 8 * 4);
  int* deg = (int*)alloc((size_t)N * 4);
  int* rowptr = (int*)alloc((size_t)(N + 1) * 4);
  int* cursor = (int*)alloc((size_t)(N + 1) * 4);
  int* colsrc = (int*)alloc((size_t)(E + N) * 4);
  int* coldst = (int*)alloc((size_t)(E + N) * 4);
  int* blockSums = (int*)alloc(256 * 4);
  int* blockOffs = (int*)alloc(256 * 4);
  __bf16* WT1h = (__bf16*)alloc(256 * 256 * 2);
  __bf16* WT2h = (__bf16*)alloc(256 * 256 * 2);
  __bf16* WT3h = (__bf16*)alloc(32 * 256 * 2);
  // h3agg reuses Ah (GEMM3 already consumed Ah/Al when agg3 writes)
  float* h3agg = (float*)Ah;

  // --- preps: x split + W transposes + CSR build ---
  k_split<<<(N * 64 + 255) / 256, 256, 0, stream>>>(x, Ah, Al, N * 64);
  k_wprep<<<(256 * 256 + 255) / 256, 256, 0, stream>>>(W1, WT1h, 256, 256);
  k_wprep<<<(256 * 256 + 255) / 256, 256, 0, stream>>>(W2, WT2h, 256, 256);
  k_wprep<<<(256 * 32 + 255) / 256, 256, 0, stream>>>(W3, WT3h, 256, 32);
  k_init_deg<<<(N + 255) / 256, 256, 0, stream>>>(deg, N);
  k_count_deg<<<(E + 255) / 256, 256, 0, stream>>>(ei, E, deg);
  const int nb = (N + 256 * SCAN_CH - 1) / (256 * SCAN_CH);  // 49 <= 256
  k_scan_partial<<<nb, 256, 0, stream>>>(deg, blockSums, N);
  k_scan_blocksums<<<1, 256, 0, stream>>>(blockSums, blockOffs, rowptr, nb, N);
  k_scan_final<<<nb, 256, 0, stream>>>(deg, blockOffs, rowptr, cursor, N);
  k_scatter<<<(E + N + 255) / 256, 256, 0, stream>>>(ei, E, N, cursor, colsrc, coldst);

  const int aggBlocks = (N + 3) / 4;
  const int gemmBlocks = (N + 63) / 64;  // 64 rows/block, full 256-col width
  const int M = E + N;
  const int edgeBlocks = (M + 255) / 256;
  dim3 g3(1, (N + 63) / 64);

  // --- layer 1 ---
  k_gemm_lds<<<gemmBlocks, 256, 0, stream>>>(Ah, Al, WT1h, Hh, Hf8, N, 256);
  k_att<<<(N * 8 + 255) / 256, 256, 0, stream>>>(Hh, as1, ad1, aS, aD, N * 8, 8);
  k_edge_alpha8<<<edgeBlocks, 256, 0, stream>>>(aS, aD, colsrc, coldst, ealpha, M);
  k_gat_agg8<<<aggBlocks, 256, 0, stream>>>(Hf8, rowptr, colsrc, ealpha, b1,
                                            Ah, Al, N);
  // --- layer 2 ---
  k_gemm_lds<<<gemmBlocks, 256, 0, stream>>>(Ah, Al, WT2h, Hh, Hf8, N, 256);
  k_att<<<(N * 8 + 255) / 256, 256, 0, stream>>>(Hh, as2, ad2, aS, aD, N * 8, 8);
  k_edge_alpha8<<<edgeBlocks, 256, 0, stream>>>(aS, aD, colsrc, coldst, ealpha, M);
  k_gat_agg8<<<aggBlocks, 256, 0, stream>>>(Hf8, rowptr, colsrc, ealpha, b2,
                                            Ah, Al, N);
  // --- layer 3 (H=1, bf16 gather) ---
  k_gemm_split<2, 1><<<g3, 256, 0, stream>>>(Ah, Al, WT3h, Hh, N, 256, 32);
  k_att<<<(N + 255) / 256, 256, 0, stream>>>(Hh, as3, ad3, aS, aD, N, 1);
  k_edge_alpha1<<<edgeBlocks, 256, 0, stream>>>(aS, aD, colsrc, coldst, ealpha, M);
  k_gat_agg1<<<aggBlocks, 256, 0, stream>>>(Hh, rowptr, colsrc, ealpha, b3,
                                            h3agg, N);
  // --- pool + final ---
  k_pool_final<<<NUM_GRAPHS, 256, 0, stream>>>(h3agg, batch, linW, linb, out, N);
}